// Round 3
// baseline (443.948 us; speedup 1.0000x reference)
//
#include <hip/hip_runtime.h>
#include <hip/hip_bf16.h>

typedef __attribute__((ext_vector_type(4))) float  f32x4;
typedef __attribute__((ext_vector_type(8))) __bf16 bf16x8;

#define NB 2
#define NN 100000
#define NE 400000
#define EPB 512  // edges per block in k_edges

// fast tanh: no IEEE divide (v_rcp approx, ~2^-23 rel err), med3 clamp.
__device__ __forceinline__ float tanh_f(float x) {
  float y = __builtin_amdgcn_fmed3f(2.f * x, -40.f, 40.f);
  float e = __expf(y);
  return fmaf(-2.f, __builtin_amdgcn_rcpf(e + 1.f), 1.f);
}

// dtype-branched float load: bf=1 -> buffer is bf16, bf=0 -> fp32
__device__ __forceinline__ float ldf(const void* p, long i, int bf) {
  return bf ? (float)((const __bf16*)p)[i] : ((const float*)p)[i];
}

// ---------- one-block setup: dtype detect + h_num MLP + weight-fragment pack ----------
// flags[0]=mask-is-bytes, flags[1]=inputs-are-bf16
__global__ __launch_bounds__(256) void k_setup(
    const unsigned int* __restrict__ mw, const unsigned int* __restrict__ nodew,
    const void* __restrict__ numerical, const void* __restrict__ W1,
    const void* __restrict__ b1, const void* __restrict__ W2,
    const void* __restrict__ b2, const void* __restrict__ Wn,
    const void* __restrict__ bn, const void* __restrict__ We,
    int* __restrict__ flags, float* __restrict__ hnum,
    float* __restrict__ sums, float* __restrict__ counts,
    __bf16* __restrict__ packWn, __bf16* __restrict__ packWe,
    float* __restrict__ packBn) {
  __shared__ int badS, goodS, dtS;
  __shared__ float numf[2][32];
  __shared__ float u[2][128];
  const int t = threadIdx.x;
  if (t == 0) { badS = 0; goodS = 0; }
  __syncthreads();
  int my = 0;
  for (int i = t; i < 4096; i += 256) my |= (mw[i] > 1u) ? 1 : 0;
  if (my) atomicOr(&badS, 1);
  int g = 0;
  for (int i = t; i < 4096; i += 256) {
    unsigned lo = nodew[i] & 0xFFFFu;
    unsigned e = (lo >> 7) & 0xFFu;
    g += (lo == 0u || (e >= 100u && e <= 141u)) ? 1 : 0;
  }
  atomicAdd(&goodS, g);
  __syncthreads();
  if (t == 0) {
    flags[0] = badS;
    dtS = (goodS > 2048) ? 1 : 0;
    flags[1] = dtS;
  }
  __syncthreads();
  const int dt = dtS;

  if (t < 128) sums[t] = 0.f;
  if (t < 2) counts[t] = 0.f;
  if (t < 64) numf[t >> 5][t & 31] = ldf(numerical, t, dt);
  __syncthreads();
  {
    const int b = t >> 7, j = t & 127;
    float acc = ldf(b1, j, dt);
#pragma unroll
    for (int k = 0; k < 32; ++k) acc += numf[b][k] * ldf(W1, k * 128 + j, dt);
    u[b][j] = tanh_f(acc);
  }
  __syncthreads();
  if (t < 128) {
    const int b = t >> 6, d = t & 63;
    float acc = ldf(b2, d, dt);
#pragma unroll
    for (int k = 0; k < 128; ++k) acc += u[b][k] * ldf(W2, k * 64 + d, dt);
    hnum[b * 64 + d] = tanh_f(acc);
  }

  // pack per-lane MFMA B-fragments (layout B[k=quad*8+j][n], n = m+16*nt)
  if (t < 64) {
    const int m = t & 15, quad = t >> 4;
#pragma unroll
    for (int nt = 0; nt < 4; ++nt) {
      const int c = m + 16 * nt;
#pragma unroll
      for (int j = 0; j < 8; ++j)
        packWn[t * 32 + nt * 8 + j] = (__bf16)ldf(Wn, (quad * 8 + j) * 64 + c, dt);
      packBn[t * 4 + nt] = ldf(bn, c, dt);
    }
    // We (128x64) fragments for e12 = [h1|h2] @ We: kstep s in [0,4), ntile nt.
    // frag f = s*4+nt holds B[k=32s+quad*8+j][n=m+16nt] = We[k*64+n]
    // NEW layout: packWe[(f*64 + lane)*8 + j] so k_edges can stage LDS linearly
    // and read conflict-free (fixed f -> 64 lanes cover 1KB contiguous).
#pragma unroll
    for (int f = 0; f < 16; ++f) {
      const int s = f >> 2, nt = f & 3;
      const int n = m + 16 * nt;
#pragma unroll
      for (int j = 0; j < 8; ++j) {
        const int k = s * 32 + quad * 8 + j;
        packWe[(f * 64 + t) * 8 + j] = (__bf16)ldf(We, (long)k * 64 + n, dt);
      }
    }
  }
}

// ---------- per-node MFMA: h = tanh(node@Wn+bn), stored bf16 [node][64] ----------
// block = 256 (4 waves); each wave 16 rows; grid = 200000/64 = 3125.
__global__ __launch_bounds__(256) void k_nodes(
    const void* __restrict__ node, const __bf16* __restrict__ packWn,
    const float* __restrict__ packBn, const int* __restrict__ flags,
    __bf16* __restrict__ hG) {
  const int t = threadIdx.x;
  const int wave = t >> 6, lane = t & 63;
  const int m = lane & 15, quad = lane >> 4;
  const int dt = flags[1];

  bf16x8 wnF[4];
#pragma unroll
  for (int nt = 0; nt < 4; ++nt)
    wnF[nt] = *(const bf16x8*)(packWn + lane * 32 + nt * 8);
  float bnv[4];
#pragma unroll
  for (int nt = 0; nt < 4; ++nt) bnv[nt] = packBn[lane * 4 + nt];

  const long r0 = ((long)blockIdx.x * 4 + wave) * 16;
  // A-frag: A[m=lane&15][k=quad*8+j]
  bf16x8 aF;
  if (dt) {
    aF = *(const bf16x8*)((const __bf16*)node + (r0 + m) * 32 + quad * 8);
  } else {
    const float* p = (const float*)node + (r0 + m) * 32 + quad * 8;
    f32x4 v0 = *(const f32x4*)p, v1 = *(const f32x4*)(p + 4);
#pragma unroll
    for (int j = 0; j < 4; ++j) { aF[j] = (__bf16)v0[j]; aF[4 + j] = (__bf16)v1[j]; }
  }

  f32x4 acc[4];
#pragma unroll
  for (int nt = 0; nt < 4; ++nt) {
    f32x4 c; c[0] = bnv[nt]; c[1] = bnv[nt]; c[2] = bnv[nt]; c[3] = bnv[nt];
    acc[nt] = c;
  }
#pragma unroll
  for (int nt = 0; nt < 4; ++nt)
    acc[nt] = __builtin_amdgcn_mfma_f32_16x16x32_bf16(aF, wnF[nt], acc[nt], 0, 0, 0);

  // C layout: row = quad*4+r (node in tile), col = m+16nt (h dim). Direct 2B
  // stores through L2 (contiguous 8KB per block; L2 merges sectors).
  __bf16* out = hG + r0 * 64;
#pragma unroll
  for (int nt = 0; nt < 4; ++nt)
#pragma unroll
    for (int r = 0; r < 4; ++r)
      out[(quad * 4 + r) * 64 + m + 16 * nt] = (__bf16)tanh_f(acc[nt][r]);
}

// ---------- per-edge: gather h rows (256B/edge), per-edge MFMA both directions ----------
// e12 = [h1|h2]@We, e21 = [h2|h1]@We (same regs, K-halves swapped).
// block = 256 = 4 waves; wave handles 8 tiles of 16 edges -> 512 edges/block.
// Depth-2 gather prefetch (3 rotating A-frag sets, static indices): 8 loads
// in flight per wave. We fragments live in LDS (shared across waves,
// conflict-free [f][lane] layout, lgkmcnt-decoupled from the gather vmcnt).
__global__ __launch_bounds__(256, 4) void k_edges(
    const int2* __restrict__ eidx, const void* __restrict__ emask,
    const int* __restrict__ flags, const __bf16* __restrict__ hG,
    const __bf16* __restrict__ packWe, const void* __restrict__ be,
    float* __restrict__ sums, float* __restrict__ counts,
    float* __restrict__ outp) {
  const int nbPerB = (NE + EPB - 1) / EPB;
  const int b = blockIdx.x / nbPerB;
  const long e0 = (long)(blockIdx.x % nbPerB) * EPB;
  const int t = threadIdx.x;
  const int wave = t >> 6, lane = t & 63;
  const int m = lane & 15, quad = lane >> 4;
  const int dt = flags[1], mode = flags[0];

  __shared__ __bf16 weL[64 * 128];  // [f][lane][8] = 16 KB
  __shared__ int2 eL[EPB];
  __shared__ float mL[EPB];
  __shared__ float red[4][64];
  __shared__ float redc[4];

  // stage We fragments (16 KB, 1024 x 16B chunks; 4 per thread)
  {
    const bf16x8* src = (const bf16x8*)packWe;
    bf16x8* dst = (bf16x8*)weL;
#pragma unroll
    for (int u = 0; u < 4; ++u) dst[t + 256 * u] = src[t + 256 * u];
  }
  // stage indices + mask, coalesced
#pragma unroll
  for (int u = 0; u < 2; ++u) {
    const int idx = t + 256 * u;
    const long e = e0 + idx;
    const int valid = (e < NE) ? 1 : 0;
    const long ec = valid ? e : (NE - 1);
    eL[idx] = eidx[(long)b * NE + ec];
    float mv;
    if (mode) mv = (float)(((const unsigned char*)emask)[(long)b * NE + ec]);
    else      mv = (float)(((const int*)emask)[(long)b * NE + ec]);
    mL[idx] = valid ? mv : 0.f;
  }
  __syncthreads();

  float be2[4];  // 2 * be[m+16nt]
#pragma unroll
  for (int nt = 0; nt < 4; ++nt) be2[nt] = 2.f * ldf(be, m + 16 * nt, dt);

  const __bf16* hb = hG + (long)b * NN * 64;
  const int wslot = wave * 128;
  float psum[4] = {0.f, 0.f, 0.f, 0.f};

  // rotating A-frag sets: [set][0..3] = h1 lo, h1 hi, h2 lo, h2 hi
  bf16x8 A[3][4];
#define GATHER(SET, TT)                                             \
  {                                                                 \
    const int2 ij = eL[wslot + (TT) * 16 + m];                      \
    const __bf16* hi = hb + (long)ij.x * 64;                        \
    const __bf16* hj = hb + (long)ij.y * 64;                        \
    A[SET][0] = *(const bf16x8*)(hi + quad * 8);                    \
    A[SET][1] = *(const bf16x8*)(hi + 32 + quad * 8);               \
    A[SET][2] = *(const bf16x8*)(hj + quad * 8);                    \
    A[SET][3] = *(const bf16x8*)(hj + 32 + quad * 8);               \
  }
  GATHER(0, 0)
  GATHER(1, 1)

#pragma unroll
  for (int it = 0; it < 8; ++it) {
    const int cb = it % 3;
    if (it + 2 < 8) {
      const int pb = (it + 2) % 3;
      GATHER(pb, it + 2)
    }

    f32x4 acc12[4], acc21[4];
#pragma unroll
    for (int nt = 0; nt < 4; ++nt) {
      f32x4 z; z[0] = 0.f; z[1] = 0.f; z[2] = 0.f; z[3] = 0.f;
      acc12[nt] = z; acc21[nt] = z;
    }
    // k-step s: e12 uses A[cb][s], e21 uses A[cb][s^2] (swap h1/h2 halves)
#pragma unroll
    for (int s = 0; s < 4; ++s) {
      bf16x8 w[4];
#pragma unroll
      for (int nt = 0; nt < 4; ++nt)
        w[nt] = *(const bf16x8*)(weL + ((4 * s + nt) * 64 + lane) * 8);
      const bf16x8 a12 = A[cb][s];
      const bf16x8 a21 = A[cb][s ^ 2];
#pragma unroll
      for (int nt = 0; nt < 4; ++nt) {
        acc12[nt] = __builtin_amdgcn_mfma_f32_16x16x32_bf16(a12, w[nt], acc12[nt], 0, 0, 0);
        acc21[nt] = __builtin_amdgcn_mfma_f32_16x16x32_bf16(a21, w[nt], acc21[nt], 0, 0, 0);
      }
    }

    // epilogue: C row = quad*4+r = edge in tile, col = m+16nt = dim
    const long egbase = e0 + wslot + it * 16;
#pragma unroll
    for (int r = 0; r < 4; ++r) {
      const long e = egbase + quad * 4 + r;
      if (e >= NE) continue;  // only last block; invalid edges contribute 0
      const float mvr = mL[wslot + it * 16 + quad * 4 + r];
      float* op = outp + ((long)b * NE + e) * 64 + m;
#pragma unroll
      for (int nt = 0; nt < 4; ++nt) {
        float x12 = __builtin_amdgcn_fmed3f(
            fmaf(acc12[nt][r], 2.f, be2[nt]), -40.f, 40.f);
        float x21 = __builtin_amdgcn_fmed3f(
            fmaf(acc21[nt][r], 2.f, be2[nt]), -40.f, 40.f);
        const float p12 = __builtin_amdgcn_rcpf(__expf(x12) + 1.f);
        const float p21 = __builtin_amdgcn_rcpf(__expf(x21) + 1.f);
        const float v = mvr * (1.f - p12 - p21);
        psum[nt] += v;
        // per-instr: 16 lanes x 4B contiguous per edge -> full 64B sectors
        __builtin_nontemporal_store(v, op + 16 * nt);
      }
    }
  }
#undef GATHER

  // dim-sum reduce: fold the 4 quad groups, then cross-wave via 1KB LDS
#pragma unroll
  for (int nt = 0; nt < 4; ++nt) {
    psum[nt] += __shfl_xor(psum[nt], 16);
    psum[nt] += __shfl_xor(psum[nt], 32);
  }
  if (quad == 0) {
#pragma unroll
    for (int nt = 0; nt < 4; ++nt) red[wave][m + 16 * nt] = psum[nt];
  }
  // mask count: full-wave reduce of staged mask values
  float pc = mL[t] + mL[t + 256];
#pragma unroll
  for (int d = 1; d < 64; d <<= 1) pc += __shfl_xor(pc, d);
  if (lane == 0) redc[wave] = pc;
  __syncthreads();
  if (t < 64) {
    const float s = red[0][t] + red[1][t] + red[2][t] + red[3][t];
    atomicAdd(&sums[b * 64 + t], s);
  }
  if (t == 0) atomicAdd(&counts[b], redc[0] + redc[1] + redc[2] + redc[3]);
}

// ---------- finalize state_value = [h_num | mean | stage] (fp32 out) ----------
__global__ __launch_bounds__(512) void k_final(
    const float* __restrict__ hnum, const float* __restrict__ sums,
    const float* __restrict__ counts, const void* __restrict__ stage,
    const int* __restrict__ flags, float* __restrict__ out) {
  const int t = threadIdx.x;
  const int dt = flags[1];
  if (t < 260) {
    const int b = t / 130, c = t % 130;
    float v;
    if (c < 64) v = hnum[b * 64 + c];
    else if (c < 128) v = sums[b * 64 + (c - 64)] / counts[b];
    else v = ldf(stage, b * 2 + (c - 128), dt);
    out[(long)NB * NE * 64 + (long)b * 130 + c] = v;
  }
}

extern "C" void kernel_launch(void* const* d_in, const int* in_sizes, int n_in,
                              void* d_out, int out_size, void* d_ws, size_t ws_size,
                              hipStream_t stream) {
  const void* numerical = d_in[0];
  const void* node      = d_in[1];
  const int2* eidx      = (const int2*)d_in[2];
  const void* emask     = d_in[3];
  const void* stage     = d_in[4];
  const void* W1 = d_in[5];
  const void* b1 = d_in[6];
  const void* W2 = d_in[7];
  const void* b2 = d_in[8];
  const void* Wn = d_in[9];
  const void* bn = d_in[10];
  const void* We = d_in[11];
  const void* be = d_in[12];

  char* ws = (char*)d_ws;
  int*    flags  = (int*)ws;
  float*  sums   = (float*)(ws + 256);    // [2][64]
  float*  counts = (float*)(ws + 1024);   // [2]
  float*  hnum   = (float*)(ws + 1280);   // [2][64]
  float*  packBn = (float*)(ws + 2048);   // 64*4*4B = 1 KB
  __bf16* packWn = (__bf16*)(ws + 4096);  // 64*32*2B = 4 KB
  __bf16* packWe = (__bf16*)(ws + 8192);  // 64*128*2B = 16 KB
  __bf16* hG     = (__bf16*)(ws + 32768); // 200000*64*2B = 25.6 MB
  float*  outp   = (float*)d_out;

  k_setup<<<1, 256, 0, stream>>>((const unsigned int*)emask, (const unsigned int*)node,
                                 numerical, W1, b1, W2, b2, Wn, bn, We,
                                 flags, hnum, sums, counts, packWn, packWe, packBn);
  k_nodes<<<(NB * NN) / 64, 256, 0, stream>>>(node, packWn, packBn, flags, hG);
  k_edges<<<NB * ((NE + EPB - 1) / EPB), 256, 0, stream>>>(eidx, emask, flags, hG, packWe, be,
                                                           sums, counts, outp);
  k_final<<<1, 512, 0, stream>>>(hnum, sums, counts, stage, flags, outp);
}

// Round 4
// 392.402 us; speedup vs baseline: 1.1314x; 1.1314x over previous
//
#include <hip/hip_runtime.h>
#include <hip/hip_bf16.h>

typedef __attribute__((ext_vector_type(4))) float  f32x4;
typedef __attribute__((ext_vector_type(8))) __bf16 bf16x8;

#define NB 2
#define NN 100000
#define NE 400000
#define EPB 256  // edges per block in k_edges (round-2 proven)

// fast tanh: no IEEE divide (v_rcp approx, ~2^-23 rel err), med3 clamp.
__device__ __forceinline__ float tanh_f(float x) {
  float y = __builtin_amdgcn_fmed3f(2.f * x, -40.f, 40.f);
  float e = __expf(y);
  return fmaf(-2.f, __builtin_amdgcn_rcpf(e + 1.f), 1.f);
}

// dtype-branched float load: bf=1 -> buffer is bf16, bf=0 -> fp32
__device__ __forceinline__ float ldf(const void* p, long i, int bf) {
  return bf ? (float)((const __bf16*)p)[i] : ((const float*)p)[i];
}

// ---------- one-block setup: dtype detect + h_num MLP + weight-fragment pack ----------
// flags[0]=mask-is-bytes, flags[1]=inputs-are-bf16
__global__ __launch_bounds__(256) void k_setup(
    const unsigned int* __restrict__ mw, const unsigned int* __restrict__ nodew,
    const void* __restrict__ numerical, const void* __restrict__ W1,
    const void* __restrict__ b1, const void* __restrict__ W2,
    const void* __restrict__ b2, const void* __restrict__ Wn,
    const void* __restrict__ bn, const void* __restrict__ We,
    int* __restrict__ flags, float* __restrict__ hnum,
    float* __restrict__ sums, float* __restrict__ counts,
    __bf16* __restrict__ packWn, __bf16* __restrict__ packWe,
    float* __restrict__ packBn) {
  __shared__ int badS, goodS, dtS;
  __shared__ float numf[2][32];
  __shared__ float u[2][128];
  const int t = threadIdx.x;
  if (t == 0) { badS = 0; goodS = 0; }
  __syncthreads();
  int my = 0;
  for (int i = t; i < 4096; i += 256) my |= (mw[i] > 1u) ? 1 : 0;
  if (my) atomicOr(&badS, 1);
  int g = 0;
  for (int i = t; i < 4096; i += 256) {
    unsigned lo = nodew[i] & 0xFFFFu;
    unsigned e = (lo >> 7) & 0xFFu;
    g += (lo == 0u || (e >= 100u && e <= 141u)) ? 1 : 0;
  }
  atomicAdd(&goodS, g);
  __syncthreads();
  if (t == 0) {
    flags[0] = badS;
    dtS = (goodS > 2048) ? 1 : 0;
    flags[1] = dtS;
  }
  __syncthreads();
  const int dt = dtS;

  if (t < 128) sums[t] = 0.f;
  if (t < 2) counts[t] = 0.f;
  if (t < 64) numf[t >> 5][t & 31] = ldf(numerical, t, dt);
  __syncthreads();
  {
    const int b = t >> 7, j = t & 127;
    float acc = ldf(b1, j, dt);
#pragma unroll
    for (int k = 0; k < 32; ++k) acc += numf[b][k] * ldf(W1, k * 128 + j, dt);
    u[b][j] = tanh_f(acc);
  }
  __syncthreads();
  if (t < 128) {
    const int b = t >> 6, d = t & 63;
    float acc = ldf(b2, d, dt);
#pragma unroll
    for (int k = 0; k < 128; ++k) acc += u[b][k] * ldf(W2, k * 64 + d, dt);
    hnum[b * 64 + d] = tanh_f(acc);
  }

  // pack per-lane MFMA B-fragments (layout B[k=quad*8+j][n], n = m+16*nt)
  if (t < 64) {
    const int m = t & 15, quad = t >> 4;
#pragma unroll
    for (int nt = 0; nt < 4; ++nt) {
      const int c = m + 16 * nt;
#pragma unroll
      for (int j = 0; j < 8; ++j)
        packWn[t * 32 + nt * 8 + j] = (__bf16)ldf(Wn, (quad * 8 + j) * 64 + c, dt);
      packBn[t * 4 + nt] = ldf(bn, c, dt);
    }
    // We (128x64) fragments for e12 = [h1|h2] @ We: kstep s in [0,4), ntile nt.
    // frag f = s*4+nt holds B[k=32s+quad*8+j][n=m+16nt] = We[k*64+n]
    // layout: packWe[(f*64 + lane)*8 + j] so k_edges stages LDS linearly and
    // reads conflict-free (fixed f -> 64 lanes cover 1KB contiguous).
#pragma unroll
    for (int f = 0; f < 16; ++f) {
      const int s = f >> 2, nt = f & 3;
      const int n = m + 16 * nt;
#pragma unroll
      for (int j = 0; j < 8; ++j) {
        const int k = s * 32 + quad * 8 + j;
        packWe[(f * 64 + t) * 8 + j] = (__bf16)ldf(We, (long)k * 64 + n, dt);
      }
    }
  }
}

// ---------- per-node MFMA: h = tanh(node@Wn+bn), stored bf16 [node][64] ----------
// block = 256 (4 waves); each wave 16 rows; grid = 200000/64 = 3125.
__global__ __launch_bounds__(256) void k_nodes(
    const void* __restrict__ node, const __bf16* __restrict__ packWn,
    const float* __restrict__ packBn, const int* __restrict__ flags,
    __bf16* __restrict__ hG) {
  const int t = threadIdx.x;
  const int wave = t >> 6, lane = t & 63;
  const int m = lane & 15, quad = lane >> 4;
  const int dt = flags[1];

  bf16x8 wnF[4];
#pragma unroll
  for (int nt = 0; nt < 4; ++nt)
    wnF[nt] = *(const bf16x8*)(packWn + lane * 32 + nt * 8);
  float bnv[4];
#pragma unroll
  for (int nt = 0; nt < 4; ++nt) bnv[nt] = packBn[lane * 4 + nt];

  const long r0 = ((long)blockIdx.x * 4 + wave) * 16;
  // A-frag: A[m=lane&15][k=quad*8+j]
  bf16x8 aF;
  if (dt) {
    aF = *(const bf16x8*)((const __bf16*)node + (r0 + m) * 32 + quad * 8);
  } else {
    const float* p = (const float*)node + (r0 + m) * 32 + quad * 8;
    f32x4 v0 = *(const f32x4*)p, v1 = *(const f32x4*)(p + 4);
#pragma unroll
    for (int j = 0; j < 4; ++j) { aF[j] = (__bf16)v0[j]; aF[4 + j] = (__bf16)v1[j]; }
  }

  f32x4 acc[4];
#pragma unroll
  for (int nt = 0; nt < 4; ++nt) {
    f32x4 c; c[0] = bnv[nt]; c[1] = bnv[nt]; c[2] = bnv[nt]; c[3] = bnv[nt];
    acc[nt] = c;
  }
#pragma unroll
  for (int nt = 0; nt < 4; ++nt)
    acc[nt] = __builtin_amdgcn_mfma_f32_16x16x32_bf16(aF, wnF[nt], acc[nt], 0, 0, 0);

  // C layout: row = quad*4+r (node in tile), col = m+16nt (h dim). Direct 2B
  // stores through L2 (contiguous 8KB per block; L2 merges sectors).
  __bf16* out = hG + r0 * 64;
#pragma unroll
  for (int nt = 0; nt < 4; ++nt)
#pragma unroll
    for (int r = 0; r < 4; ++r)
      out[(quad * 4 + r) * 64 + m + 16 * nt] = (__bf16)tanh_f(acc[nt][r]);
}

// ---------- per-edge: gather h rows (256B/edge), per-edge MFMA both directions ----------
// e12 = [h1|h2]@We, e21 = [h2|h1]@We (same regs, K-halves swapped).
// block = 256 = 4 waves; wave handles 4 tiles of 16 edges -> 256 edges/block.
// Round-2 loop structure (depth-1 prefetch, proven no-spill) with We moved to
// LDS: cuts ~64 unified regs -> target 4 waves/SIMD (2x occupancy, 2x MLP).
__global__ __launch_bounds__(256) void k_edges(
    const int2* __restrict__ eidx, const void* __restrict__ emask,
    const int* __restrict__ flags, const __bf16* __restrict__ hG,
    const __bf16* __restrict__ packWe, const void* __restrict__ be,
    float* __restrict__ sums, float* __restrict__ counts,
    float* __restrict__ outp) {
  const int nbPerB = (NE + EPB - 1) / EPB;
  const int b = blockIdx.x / nbPerB;
  const long e0 = (long)(blockIdx.x % nbPerB) * EPB;
  const int t = threadIdx.x;
  const int wave = t >> 6, lane = t & 63;
  const int m = lane & 15, quad = lane >> 4;
  const int dt = flags[1], mode = flags[0];

  __shared__ __bf16 weL[64 * 128];  // [f][lane][8] = 16 KB
  __shared__ int2 eL[EPB];
  __shared__ float mL[EPB];
  __shared__ float red[4][64];
  __shared__ float redc[4];

  // stage We fragments (16 KB, 1024 x 16B chunks; 4 per thread)
  {
    const bf16x8* src = (const bf16x8*)packWe;
    bf16x8* dst = (bf16x8*)weL;
#pragma unroll
    for (int u = 0; u < 4; ++u) dst[t + 256 * u] = src[t + 256 * u];
  }
  // stage indices + mask once, coalesced
  {
    const long e = e0 + t;
    const int valid = (e < NE) ? 1 : 0;
    const long ec = valid ? e : (NE - 1);
    eL[t] = eidx[(long)b * NE + ec];
    float mv;
    if (mode) mv = (float)(((const unsigned char*)emask)[(long)b * NE + ec]);
    else      mv = (float)(((const int*)emask)[(long)b * NE + ec]);
    mL[t] = valid ? mv : 0.f;
  }
  __syncthreads();

  float be2[4];  // 2 * be[m+16nt]
#pragma unroll
  for (int nt = 0; nt < 4; ++nt) be2[nt] = 2.f * ldf(be, m + 16 * nt, dt);

  const __bf16* hb = hG + (long)b * NN * 64;
  float psum[4] = {0.f, 0.f, 0.f, 0.f};

  // prefetch tile 0
  bf16x8 a0, a1, a2, a3;
  {
    const int2 ij = eL[wave * 64 + m];
    const __bf16* hi = hb + (long)ij.x * 64;
    const __bf16* hj = hb + (long)ij.y * 64;
    a0 = *(const bf16x8*)(hi + quad * 8);
    a1 = *(const bf16x8*)(hi + 32 + quad * 8);
    a2 = *(const bf16x8*)(hj + quad * 8);
    a3 = *(const bf16x8*)(hj + 32 + quad * 8);
  }

#pragma unroll
  for (int it = 0; it < 4; ++it) {
    const int slot = wave * 64 + it * 16;
    // current tile frags
    const bf16x8 c0 = a0, c1 = a1, c2 = a2, c3 = a3;
    // issue next tile's gathers now; MFMA+epilogue below hides their latency
    if (it < 3) {
      const int2 ij = eL[slot + 16 + m];
      const __bf16* hi = hb + (long)ij.x * 64;
      const __bf16* hj = hb + (long)ij.y * 64;
      a0 = *(const bf16x8*)(hi + quad * 8);
      a1 = *(const bf16x8*)(hi + 32 + quad * 8);
      a2 = *(const bf16x8*)(hj + quad * 8);
      a3 = *(const bf16x8*)(hj + 32 + quad * 8);
    }

    f32x4 acc12[4], acc21[4];
#pragma unroll
    for (int nt = 0; nt < 4; ++nt) {
      f32x4 z; z[0] = 0.f; z[1] = 0.f; z[2] = 0.f; z[3] = 0.f;
      acc12[nt] = z; acc21[nt] = z;
    }
    // k-step s: e12 uses cur[s], e21 uses cur[s^2] (swap h1/h2 halves);
    // B-frags streamed from LDS (frag f = 4s+nt at [f*64+lane]*8).
#pragma unroll
    for (int s = 0; s < 4; ++s) {
      bf16x8 w[4];
#pragma unroll
      for (int nt = 0; nt < 4; ++nt)
        w[nt] = *(const bf16x8*)(weL + ((4 * s + nt) * 64 + lane) * 8);
      const bf16x8 a12 = (s == 0) ? c0 : (s == 1) ? c1 : (s == 2) ? c2 : c3;
      const bf16x8 a21 = (s == 0) ? c2 : (s == 1) ? c3 : (s == 2) ? c0 : c1;
#pragma unroll
      for (int nt = 0; nt < 4; ++nt) {
        acc12[nt] = __builtin_amdgcn_mfma_f32_16x16x32_bf16(a12, w[nt], acc12[nt], 0, 0, 0);
        acc21[nt] = __builtin_amdgcn_mfma_f32_16x16x32_bf16(a21, w[nt], acc21[nt], 0, 0, 0);
      }
    }

    // epilogue: C row = quad*4+r = edge in tile, col = m+16nt = dim
    const long egbase = e0 + slot;
#pragma unroll
    for (int r = 0; r < 4; ++r) {
      const long e = egbase + quad * 4 + r;
      if (e >= NE) continue;  // only last block; invalid edges contribute 0
      const float mvr = mL[slot + quad * 4 + r];
      float* op = outp + ((long)b * NE + e) * 64 + m;
#pragma unroll
      for (int nt = 0; nt < 4; ++nt) {
        float x12 = __builtin_amdgcn_fmed3f(
            fmaf(acc12[nt][r], 2.f, be2[nt]), -40.f, 40.f);
        float x21 = __builtin_amdgcn_fmed3f(
            fmaf(acc21[nt][r], 2.f, be2[nt]), -40.f, 40.f);
        const float p12 = __builtin_amdgcn_rcpf(__expf(x12) + 1.f);
        const float p21 = __builtin_amdgcn_rcpf(__expf(x21) + 1.f);
        const float v = mvr * (1.f - p12 - p21);
        psum[nt] += v;
        // per-instr: 16 lanes x 4B contiguous per edge -> full 64B sectors
        __builtin_nontemporal_store(v, op + 16 * nt);
      }
    }
  }

  // dim-sum reduce: fold the 4 quad groups, then cross-wave via 1KB LDS
#pragma unroll
  for (int nt = 0; nt < 4; ++nt) {
    psum[nt] += __shfl_xor(psum[nt], 16);
    psum[nt] += __shfl_xor(psum[nt], 32);
  }
  if (quad == 0) {
#pragma unroll
    for (int nt = 0; nt < 4; ++nt) red[wave][m + 16 * nt] = psum[nt];
  }
  // mask count: full-wave reduce of staged mask values
  float pc = mL[t];
#pragma unroll
  for (int d = 1; d < 64; d <<= 1) pc += __shfl_xor(pc, d);
  if (lane == 0) redc[wave] = pc;
  __syncthreads();
  if (t < 64) {
    const float s = red[0][t] + red[1][t] + red[2][t] + red[3][t];
    atomicAdd(&sums[b * 64 + t], s);
  }
  if (t == 0) atomicAdd(&counts[b], redc[0] + redc[1] + redc[2] + redc[3]);
}

// ---------- finalize state_value = [h_num | mean | stage] (fp32 out) ----------
__global__ __launch_bounds__(512) void k_final(
    const float* __restrict__ hnum, const float* __restrict__ sums,
    const float* __restrict__ counts, const void* __restrict__ stage,
    const int* __restrict__ flags, float* __restrict__ out) {
  const int t = threadIdx.x;
  const int dt = flags[1];
  if (t < 260) {
    const int b = t / 130, c = t % 130;
    float v;
    if (c < 64) v = hnum[b * 64 + c];
    else if (c < 128) v = sums[b * 64 + (c - 64)] / counts[b];
    else v = ldf(stage, b * 2 + (c - 128), dt);
    out[(long)NB * NE * 64 + (long)b * 130 + c] = v;
  }
}

extern "C" void kernel_launch(void* const* d_in, const int* in_sizes, int n_in,
                              void* d_out, int out_size, void* d_ws, size_t ws_size,
                              hipStream_t stream) {
  const void* numerical = d_in[0];
  const void* node      = d_in[1];
  const int2* eidx      = (const int2*)d_in[2];
  const void* emask     = d_in[3];
  const void* stage     = d_in[4];
  const void* W1 = d_in[5];
  const void* b1 = d_in[6];
  const void* W2 = d_in[7];
  const void* b2 = d_in[8];
  const void* Wn = d_in[9];
  const void* bn = d_in[10];
  const void* We = d_in[11];
  const void* be = d_in[12];

  char* ws = (char*)d_ws;
  int*    flags  = (int*)ws;
  float*  sums   = (float*)(ws + 256);    // [2][64]
  float*  counts = (float*)(ws + 1024);   // [2]
  float*  hnum   = (float*)(ws + 1280);   // [2][64]
  float*  packBn = (float*)(ws + 2048);   // 64*4*4B = 1 KB
  __bf16* packWn = (__bf16*)(ws + 4096);  // 64*32*2B = 4 KB
  __bf16* packWe = (__bf16*)(ws + 8192);  // 64*128*2B = 16 KB
  __bf16* hG     = (__bf16*)(ws + 32768); // 200000*64*2B = 25.6 MB
  float*  outp   = (float*)d_out;

  k_setup<<<1, 256, 0, stream>>>((const unsigned int*)emask, (const unsigned int*)node,
                                 numerical, W1, b1, W2, b2, Wn, bn, We,
                                 flags, hnum, sums, counts, packWn, packWe, packBn);
  k_nodes<<<(NB * NN) / 64, 256, 0, stream>>>(node, packWn, packBn, flags, hG);
  k_edges<<<NB * ((NE + EPB - 1) / EPB), 256, 0, stream>>>(eidx, emask, flags, hG, packWe, be,
                                                           sums, counts, outp);
  k_final<<<1, 512, 0, stream>>>(hnum, sums, counts, stage, flags, outp);
}

// Round 5
// 354.447 us; speedup vs baseline: 1.2525x; 1.1071x over previous
//
#include <hip/hip_runtime.h>
#include <hip/hip_bf16.h>

typedef __attribute__((ext_vector_type(4))) float  f32x4;
typedef __attribute__((ext_vector_type(8))) __bf16 bf16x8;

#define NB 2
#define NN 100000
#define NE 400000
#define EPB 256  // edges per block in k_edges

// fast tanh: no IEEE divide (v_rcp approx, ~2^-23 rel err), med3 clamp.
__device__ __forceinline__ float tanh_f(float x) {
  float y = __builtin_amdgcn_fmed3f(2.f * x, -40.f, 40.f);
  float e = __expf(y);
  return fmaf(-2.f, __builtin_amdgcn_rcpf(e + 1.f), 1.f);
}

// dtype-branched float load: bf=1 -> buffer is bf16, bf=0 -> fp32
__device__ __forceinline__ float ldf(const void* p, long i, int bf) {
  return bf ? (float)((const __bf16*)p)[i] : ((const float*)p)[i];
}

// ---------- one-block setup: dtype detect + h_num MLP + weight-fragment pack ----------
// flags[0]=mask-is-bytes, flags[1]=inputs-are-bf16
__global__ __launch_bounds__(256) void k_setup(
    const unsigned int* __restrict__ mw, const unsigned int* __restrict__ nodew,
    const void* __restrict__ numerical, const void* __restrict__ W1,
    const void* __restrict__ b1, const void* __restrict__ W2,
    const void* __restrict__ b2, const void* __restrict__ Wn,
    const void* __restrict__ bn, const void* __restrict__ We,
    int* __restrict__ flags, float* __restrict__ hnum,
    float* __restrict__ sums, float* __restrict__ counts,
    __bf16* __restrict__ packWn, __bf16* __restrict__ packWe,
    float* __restrict__ packBn) {
  __shared__ int badS, goodS, dtS;
  __shared__ float numf[2][32];
  __shared__ float u[2][128];
  const int t = threadIdx.x;
  if (t == 0) { badS = 0; goodS = 0; }
  __syncthreads();
  int my = 0;
  for (int i = t; i < 4096; i += 256) my |= (mw[i] > 1u) ? 1 : 0;
  if (my) atomicOr(&badS, 1);
  int g = 0;
  for (int i = t; i < 4096; i += 256) {
    unsigned lo = nodew[i] & 0xFFFFu;
    unsigned e = (lo >> 7) & 0xFFu;
    g += (lo == 0u || (e >= 100u && e <= 141u)) ? 1 : 0;
  }
  atomicAdd(&goodS, g);
  __syncthreads();
  if (t == 0) {
    flags[0] = badS;
    dtS = (goodS > 2048) ? 1 : 0;
    flags[1] = dtS;
  }
  __syncthreads();
  const int dt = dtS;

  if (t < 128) sums[t] = 0.f;
  if (t < 2) counts[t] = 0.f;
  if (t < 64) numf[t >> 5][t & 31] = ldf(numerical, t, dt);
  __syncthreads();
  {
    const int b = t >> 7, j = t & 127;
    float acc = ldf(b1, j, dt);
#pragma unroll
    for (int k = 0; k < 32; ++k) acc += numf[b][k] * ldf(W1, k * 128 + j, dt);
    u[b][j] = tanh_f(acc);
  }
  __syncthreads();
  if (t < 128) {
    const int b = t >> 6, d = t & 63;
    float acc = ldf(b2, d, dt);
#pragma unroll
    for (int k = 0; k < 128; ++k) acc += u[b][k] * ldf(W2, k * 64 + d, dt);
    hnum[b * 64 + d] = tanh_f(acc);
  }

  // pack per-lane MFMA B-fragments (layout B[k=quad*8+j][n], n = m+16*nt)
  if (t < 64) {
    const int m = t & 15, quad = t >> 4;
#pragma unroll
    for (int nt = 0; nt < 4; ++nt) {
      const int c = m + 16 * nt;
#pragma unroll
      for (int j = 0; j < 8; ++j)
        packWn[t * 32 + nt * 8 + j] = (__bf16)ldf(Wn, (quad * 8 + j) * 64 + c, dt);
      packBn[t * 4 + nt] = ldf(bn, c, dt);
    }
  }
  // We (128x64) fragments for e12 = [h1|h2] @ We, parallel over all 256 thr.
  // frag f = s*4+nt holds B[k=32s+quad*8+j][n=m+16nt] = We[k*64+n];
  // layout packWe[(f*64+lane)*8+j]: thread t handles f = (t>>6)*4 + ff.
  {
    const int lane = t & 63, fg = t >> 6;
    const int m2 = lane & 15, quad2 = lane >> 4;
#pragma unroll
    for (int ff = 0; ff < 4; ++ff) {
      const int f = fg * 4 + ff;
      const int n = m2 + 16 * ff;  // nt = ff, s = fg
#pragma unroll
      for (int j = 0; j < 8; ++j) {
        const int k = fg * 32 + quad2 * 8 + j;
        packWe[(f * 64 + lane) * 8 + j] = (__bf16)ldf(We, (long)k * 64 + n, dt);
      }
    }
  }
}

// ---------- per-node MFMA: h = tanh(node@Wn+bn), stored bf16 [node][64] ----------
// block = 256 (4 waves); each wave 16 rows; grid = 200000/64 = 3125.
__global__ __launch_bounds__(256) void k_nodes(
    const void* __restrict__ node, const __bf16* __restrict__ packWn,
    const float* __restrict__ packBn, const int* __restrict__ flags,
    __bf16* __restrict__ hG) {
  const int t = threadIdx.x;
  const int wave = t >> 6, lane = t & 63;
  const int m = lane & 15, quad = lane >> 4;
  const int dt = flags[1];

  bf16x8 wnF[4];
#pragma unroll
  for (int nt = 0; nt < 4; ++nt)
    wnF[nt] = *(const bf16x8*)(packWn + lane * 32 + nt * 8);
  float bnv[4];
#pragma unroll
  for (int nt = 0; nt < 4; ++nt) bnv[nt] = packBn[lane * 4 + nt];

  const long r0 = ((long)blockIdx.x * 4 + wave) * 16;
  // A-frag: A[m=lane&15][k=quad*8+j]
  bf16x8 aF;
  if (dt) {
    aF = *(const bf16x8*)((const __bf16*)node + (r0 + m) * 32 + quad * 8);
  } else {
    const float* p = (const float*)node + (r0 + m) * 32 + quad * 8;
    f32x4 v0 = *(const f32x4*)p, v1 = *(const f32x4*)(p + 4);
#pragma unroll
    for (int j = 0; j < 4; ++j) { aF[j] = (__bf16)v0[j]; aF[4 + j] = (__bf16)v1[j]; }
  }

  f32x4 acc[4];
#pragma unroll
  for (int nt = 0; nt < 4; ++nt) {
    f32x4 c; c[0] = bnv[nt]; c[1] = bnv[nt]; c[2] = bnv[nt]; c[3] = bnv[nt];
    acc[nt] = c;
  }
#pragma unroll
  for (int nt = 0; nt < 4; ++nt)
    acc[nt] = __builtin_amdgcn_mfma_f32_16x16x32_bf16(aF, wnF[nt], acc[nt], 0, 0, 0);

  // C layout: row = quad*4+r (node in tile), col = m+16nt (h dim).
  __bf16* out = hG + r0 * 64;
#pragma unroll
  for (int nt = 0; nt < 4; ++nt)
#pragma unroll
    for (int r = 0; r < 4; ++r)
      out[(quad * 4 + r) * 64 + m + 16 * nt] = (__bf16)tanh_f(acc[nt][r]);
}

// ---------- per-edge: in-block mask compaction + gather + MFMA both directions ----------
// ~50% of edges are masked: they need only a 256B zero row (written dense by
// 4-lane groups). Unmasked slots are compacted into cS[] via ballot prefix-sum;
// waves process ceil(cnt/16) tiles over the compacted list (round-4 core:
// depth-1 prefetch, weL in LDS, e21 = K-half-swapped e12).
__global__ __launch_bounds__(256) void k_edges(
    const int2* __restrict__ eidx, const void* __restrict__ emask,
    const int* __restrict__ flags, const __bf16* __restrict__ hG,
    const __bf16* __restrict__ packWe, const void* __restrict__ be,
    float* __restrict__ sums, float* __restrict__ counts,
    float* __restrict__ outp) {
  const int nbPerB = (NE + EPB - 1) / EPB;
  const int b = blockIdx.x / nbPerB;
  const long e0 = (long)(blockIdx.x % nbPerB) * EPB;
  const int t = threadIdx.x;
  const int wave = t >> 6, lane = t & 63;
  const int m = lane & 15, quad = lane >> 4;
  const int dt = flags[1], mode = flags[0];

  __shared__ __bf16 weL[64 * 128];  // [f][lane][8] = 16 KB
  __shared__ int2 eL[EPB];
  __shared__ float mL[EPB];
  __shared__ unsigned short cS[EPB];  // compacted slot ids
  __shared__ int wcnt[4];
  __shared__ float red[4][64];

  // stage We fragments (16 KB, 1024 x 16B chunks; 4 per thread)
  {
    const bf16x8* src = (const bf16x8*)packWe;
    bf16x8* dst = (bf16x8*)weL;
#pragma unroll
    for (int u = 0; u < 4; ++u) dst[t + 256 * u] = src[t + 256 * u];
  }
  // stage indices + mask once, coalesced; kept flag lives in-register
  int kept;
  {
    const long e = e0 + t;
    const int valid = (e < NE) ? 1 : 0;
    const long ec = valid ? e : (NE - 1);
    eL[t] = eidx[(long)b * NE + ec];
    float mv;
    if (mode) mv = (float)(((const unsigned char*)emask)[(long)b * NE + ec]);
    else      mv = (float)(((const int*)emask)[(long)b * NE + ec]);
    mv = valid ? mv : 0.f;
    mL[t] = mv;
    kept = (mv != 0.f) ? 1 : 0;
  }
  // wave-level compaction bookkeeping (register-only, pre-barrier)
  const unsigned long long bal = __ballot(kept);
  const int lpos = __popcll(bal & ((1ull << lane) - 1ull));
  if (lane == 0) wcnt[wave] = __popcll(bal);
  __syncthreads();

  int woff = 0, cntTot = 0;
#pragma unroll
  for (int w = 0; w < 4; ++w) {
    cntTot += wcnt[w];
    if (w < wave) woff += wcnt[w];
  }
  if (kept) cS[woff + lpos] = (unsigned short)t;

  // masked rows -> dense zero writes: 4-lane group per edge row (64B/lane-pair
  // per instr: 16 groups x 64B contiguous = full sectors).
  {
    const int g = lane >> 2, gi = lane & 3;
    const f32x4 z = {0.f, 0.f, 0.f, 0.f};
#pragma unroll
    for (int p = 0; p < 4; ++p) {
      const int slot = wave * 64 + p * 16 + g;
      const long e = e0 + slot;
      if (e < NE && mL[slot] == 0.f) {
        float* op = outp + ((long)b * NE + e) * 64 + gi * 16;
        __builtin_nontemporal_store(z, (f32x4*)op);
        __builtin_nontemporal_store(z, (f32x4*)(op + 4));
        __builtin_nontemporal_store(z, (f32x4*)(op + 8));
        __builtin_nontemporal_store(z, (f32x4*)(op + 12));
      }
    }
  }

  float be2[4];  // 2 * be[m+16nt]
#pragma unroll
  for (int nt = 0; nt < 4; ++nt) be2[nt] = 2.f * ldf(be, m + 16 * nt, dt);
  __syncthreads();  // cS ready

  const __bf16* hb = hG + (long)b * NN * 64;
  const int ntiles = (cntTot + 15) >> 4;
  float psum[4] = {0.f, 0.f, 0.f, 0.f};

  bf16x8 a0, a1, a2, a3;
#define GATHERT(TB)                                                 \
  {                                                                 \
    int idx_ = (TB) + m;                                            \
    if (idx_ >= cntTot) idx_ = cntTot - 1;                          \
    const int s_ = cS[idx_];                                        \
    const int2 ij = eL[s_];                                         \
    const __bf16* hi = hb + (long)ij.x * 64;                        \
    const __bf16* hj = hb + (long)ij.y * 64;                        \
    a0 = *(const bf16x8*)(hi + quad * 8);                           \
    a1 = *(const bf16x8*)(hi + 32 + quad * 8);                      \
    a2 = *(const bf16x8*)(hj + quad * 8);                           \
    a3 = *(const bf16x8*)(hj + 32 + quad * 8);                      \
  }

  int tt = wave;
  if (tt < ntiles) GATHERT(tt * 16)
  for (; tt < ntiles; tt += 4) {
    const bf16x8 c0 = a0, c1 = a1, c2 = a2, c3 = a3;
    // issue this wave's next tile's gathers; MFMA+epilogue hides latency
    if (tt + 4 < ntiles) GATHERT((tt + 4) * 16)

    f32x4 acc12[4], acc21[4];
#pragma unroll
    for (int nt = 0; nt < 4; ++nt) {
      f32x4 z; z[0] = 0.f; z[1] = 0.f; z[2] = 0.f; z[3] = 0.f;
      acc12[nt] = z; acc21[nt] = z;
    }
    // k-step s: e12 uses cur[s], e21 uses cur[s^2] (swap h1/h2 halves);
    // B-frags streamed from LDS (frag f = 4s+nt at [f*64+lane]*8).
#pragma unroll
    for (int s = 0; s < 4; ++s) {
      bf16x8 w[4];
#pragma unroll
      for (int nt = 0; nt < 4; ++nt)
        w[nt] = *(const bf16x8*)(weL + ((4 * s + nt) * 64 + lane) * 8);
      const bf16x8 a12 = (s == 0) ? c0 : (s == 1) ? c1 : (s == 2) ? c2 : c3;
      const bf16x8 a21 = (s == 0) ? c2 : (s == 1) ? c3 : (s == 2) ? c0 : c1;
#pragma unroll
      for (int nt = 0; nt < 4; ++nt) {
        acc12[nt] = __builtin_amdgcn_mfma_f32_16x16x32_bf16(a12, w[nt], acc12[nt], 0, 0, 0);
        acc21[nt] = __builtin_amdgcn_mfma_f32_16x16x32_bf16(a21, w[nt], acc21[nt], 0, 0, 0);
      }
    }

    // epilogue: C row = quad*4+r = compacted edge, col = m+16nt = dim.
    // 0.5(tanh(a)+tanh(b)) = 1 - (E1+E2+2)/((E1+1)(E2+1)), one rcp.
#pragma unroll
    for (int r = 0; r < 4; ++r) {
      const int erow = tt * 16 + quad * 4 + r;
      if (erow >= cntTot) continue;
      const long e = e0 + cS[erow];
      float* op = outp + ((long)b * NE + e) * 64 + m;
#pragma unroll
      for (int nt = 0; nt < 4; ++nt) {
        const float x12 = __builtin_amdgcn_fmed3f(
            fmaf(acc12[nt][r], 2.f, be2[nt]), -40.f, 40.f);
        const float x21 = __builtin_amdgcn_fmed3f(
            fmaf(acc21[nt][r], 2.f, be2[nt]), -40.f, 40.f);
        const float E1 = __expf(x12);
        const float E2 = __expf(x21);
        const float sE = E1 + E2;
        const float den = fmaf(E1, E2, sE + 1.f);
        const float v = fmaf(-(sE + 2.f), __builtin_amdgcn_rcpf(den), 1.f);
        psum[nt] += v;
        __builtin_nontemporal_store(v, op + 16 * nt);
      }
    }
  }
#undef GATHERT

  // dim-sum reduce: fold the 4 quad groups, then cross-wave via 1KB LDS
#pragma unroll
  for (int nt = 0; nt < 4; ++nt) {
    psum[nt] += __shfl_xor(psum[nt], 16);
    psum[nt] += __shfl_xor(psum[nt], 32);
  }
  if (quad == 0) {
#pragma unroll
    for (int nt = 0; nt < 4; ++nt) red[wave][m + 16 * nt] = psum[nt];
  }
  __syncthreads();
  if (t < 64) {
    const float s = red[0][t] + red[1][t] + red[2][t] + red[3][t];
    atomicAdd(&sums[b * 64 + t], s);
  }
  if (t == 0) atomicAdd(&counts[b], (float)cntTot);
}

// ---------- finalize state_value = [h_num | mean | stage] (fp32 out) ----------
__global__ __launch_bounds__(512) void k_final(
    const float* __restrict__ hnum, const float* __restrict__ sums,
    const float* __restrict__ counts, const void* __restrict__ stage,
    const int* __restrict__ flags, float* __restrict__ out) {
  const int t = threadIdx.x;
  const int dt = flags[1];
  if (t < 260) {
    const int b = t / 130, c = t % 130;
    float v;
    if (c < 64) v = hnum[b * 64 + c];
    else if (c < 128) v = sums[b * 64 + (c - 64)] / counts[b];
    else v = ldf(stage, b * 2 + (c - 128), dt);
    out[(long)NB * NE * 64 + (long)b * 130 + c] = v;
  }
}

extern "C" void kernel_launch(void* const* d_in, const int* in_sizes, int n_in,
                              void* d_out, int out_size, void* d_ws, size_t ws_size,
                              hipStream_t stream) {
  const void* numerical = d_in[0];
  const void* node      = d_in[1];
  const int2* eidx      = (const int2*)d_in[2];
  const void* emask     = d_in[3];
  const void* stage     = d_in[4];
  const void* W1 = d_in[5];
  const void* b1 = d_in[6];
  const void* W2 = d_in[7];
  const void* b2 = d_in[8];
  const void* Wn = d_in[9];
  const void* bn = d_in[10];
  const void* We = d_in[11];
  const void* be = d_in[12];

  char* ws = (char*)d_ws;
  int*    flags  = (int*)ws;
  float*  sums   = (float*)(ws + 256);    // [2][64]
  float*  counts = (float*)(ws + 1024);   // [2]
  float*  hnum   = (float*)(ws + 1280);   // [2][64]
  float*  packBn = (float*)(ws + 2048);   // 64*4*4B = 1 KB
  __bf16* packWn = (__bf16*)(ws + 4096);  // 64*32*2B = 4 KB
  __bf16* packWe = (__bf16*)(ws + 8192);  // 64*128*2B = 16 KB
  __bf16* hG     = (__bf16*)(ws + 32768); // 200000*64*2B = 25.6 MB
  float*  outp   = (float*)d_out;

  k_setup<<<1, 256, 0, stream>>>((const unsigned int*)emask, (const unsigned int*)node,
                                 numerical, W1, b1, W2, b2, Wn, bn, We,
                                 flags, hnum, sums, counts, packWn, packWe, packBn);
  k_nodes<<<(NB * NN) / 64, 256, 0, stream>>>(node, packWn, packBn, flags, hG);
  k_edges<<<NB * ((NE + EPB - 1) / EPB), 256, 0, stream>>>(eidx, emask, flags, hG, packWe, be,
                                                           sums, counts, outp);
  k_final<<<1, 512, 0, stream>>>(hnum, sums, counts, stage, flags, outp);
}